// Round 1
// baseline (452.919 us; speedup 1.0000x reference)
//
#include <hip/hip_runtime.h>

#define FNUM 40
#define DIM  64
#define NPAIR 780           // 40*39/2
#define BLOCK 256
#define IN4   (FNUM * DIM / 4)    // 640 float4 per batch row
#define OUT4  (NPAIR * DIM / 4)   // 12480 float4 per batch row

typedef float f32x4 __attribute__((ext_vector_type(4)));

__global__ __launch_bounds__(BLOCK, 8)   // force <=64 VGPR: 8 waves/SIMD, all 2048 blocks resident
void bilinear_fused(const float* __restrict__ in,
                    const float* __restrict__ w,
                    float* __restrict__ out)
{
    __shared__ float sXW[FNUM * DIM];   // 10 KB — the ONLY LDS; 8 blocks/CU = 80 KB/CU

    const int tid  = threadIdx.x;
    const int b    = blockIdx.x;
    const int lane = tid & 63;
    // readfirstlane: provably wave-uniform -> uniform loads below become s_load
    const int wv   = __builtin_amdgcn_readfirstlane(tid >> 6);

    // ---- GEMM phase: wave wv computes xw rows f = wv*10 .. wv*10+9 ----
    // xw[f][lane] = sum_d in[b][f][d] * w[d][lane]
    // in-row scalars via SGPR (s_load, 1 instr/MAC); W column streamed from global (L1-hot,
    // 10x register reuse per load) instead of a 64-VGPR wcol[] array.
    {
        const float* __restrict__ inw = in + (size_t)b * (FNUM * DIM) + (size_t)(wv * 10) * DIM;
        float acc[10];
        #pragma unroll
        for (int r = 0; r < 10; ++r) acc[r] = 0.f;

        #pragma unroll 4
        for (int d = 0; d < DIM; ++d) {
            float wd = w[d * DIM + lane];          // coalesced 256B/wave, L1/L2-hot
            #pragma unroll
            for (int r = 0; r < 10; ++r)
                acc[r] = fmaf(inw[r * DIM + d], wd, acc[r]);   // d-ascending: bit-identical to prev
        }
        #pragma unroll
        for (int r = 0; r < 10; ++r)
            sXW[(wv * 10 + r) * DIM + lane] = acc[r];
    }

    __syncthreads();

    // ---- pair phase: out[b, p*64 + d] = xw[i_p][d] * in[j_p][d] ----
    const f32x4* __restrict__ sXW4 = (const f32x4*)sXW;
    const f32x4* __restrict__ in4  = (const f32x4*)in  + (size_t)b * IN4;   // v_j via L1/L2
    f32x4*       __restrict__ out4 = (f32x4*)out + (size_t)b * OUT4;

    const int q = tid & 15;        // idx & 15 is invariant (stride 256)
    int i = 0;
    int j = 1 + (tid >> 4);        // p0 = tid>>4 in [0,15] -> always row 0

    // advance (i,j) by 16 pairs in combinations(range(40),2) order
    #define ADV()                                          \
        do {                                               \
            j += 16;                                       \
            while (j >= FNUM && i < FNUM) {                \
                j = (j - FNUM) + (i + 2);                  \
                ++i;                                       \
            }                                              \
        } while (0)

    #pragma unroll 4
    for (int k = 0; k < 48; ++k) {                 // 48 full strides for every thread
        int idx = tid + k * BLOCK;
        f32x4 a = sXW4[i * 16 + q];
        f32x4 v = in4[j * 16 + q];
        __builtin_nontemporal_store(a * v, &out4[idx]);
        ADV();
    }
    {   // tail: threads tid<192 have a 49th element (12480 = 48*256 + 192)
        int idx = tid + 48 * BLOCK;
        if (idx < OUT4) {
            f32x4 a = sXW4[i * 16 + q];
            f32x4 v = in4[j * 16 + q];
            __builtin_nontemporal_store(a * v, &out4[idx]);
        }
    }
    #undef ADV
}

extern "C" void kernel_launch(void* const* d_in, const int* in_sizes, int n_in,
                              void* d_out, int out_size, void* d_ws, size_t ws_size,
                              hipStream_t stream)
{
    const float* in = (const float*)d_in[0];   // [2048, 40, 64] fp32
    const float* w  = (const float*)d_in[1];   // [64, 64] fp32
    float* out = (float*)d_out;                // [2048, 780*64] fp32

    bilinear_fused<<<2048, BLOCK, 0, stream>>>(in, w, out);
}

// Round 2
// 420.967 us; speedup vs baseline: 1.0759x; 1.0759x over previous
//
#include <hip/hip_runtime.h>

#define FNUM 40
#define DIM  64
#define NPAIR 780           // 40*39/2
#define BLOCK 256
#define IN4   (FNUM * DIM / 4)    // 640 float4 per batch row
#define OUT4  (NPAIR * DIM / 4)   // 12480 float4 per batch row

typedef float f32x4 __attribute__((ext_vector_type(4)));

__global__ __launch_bounds__(BLOCK)
void bilinear_fused(const float* __restrict__ in,
                    const float* __restrict__ w,
                    float* __restrict__ out)
{
    __shared__ float sIn[FNUM * DIM];   // 10 KB
    __shared__ float sXW[FNUM * DIM];   // 10 KB
    __shared__ unsigned char sPi[NPAIR];
    __shared__ unsigned char sPj[NPAIR];

    const int tid  = threadIdx.x;
    const int b    = blockIdx.x;
    const int lane = tid & 63;
    const int wv   = tid >> 6;

    // ---- stage inputs[b] into LDS (coalesced float4) ----
    const f32x4* in4 = (const f32x4*)in + (size_t)b * IN4;
    f32x4* sIn4 = (f32x4*)sIn;
    for (int k = tid; k < IN4; k += BLOCK) sIn4[k] = in4[k];

    // ---- pair index table (once per block, trivial) ----
    if (tid < FNUM) {
        int i = tid;
        int off = i * (2 * FNUM - 1 - i) / 2;   // i*(79-i)/2, always integral
        for (int j = i + 1; j < FNUM; ++j) {
            sPi[off] = (unsigned char)i;
            sPj[off] = (unsigned char)j;
            ++off;
        }
    }

    // ---- W column `lane` into registers (coalesced per-d; L1-hot) ----
    float wcol[DIM];
    #pragma unroll
    for (int d = 0; d < DIM; ++d) wcol[d] = w[d * DIM + lane];

    __syncthreads();

    // ---- GEMM: wave wv computes rows wv*10 .. wv*10+9 ----
    // xw[f][lane] = sum_d in[f][d] * W[d][lane]; broadcast in[f][d] via readlane.
    for (int r = 0; r < 10; ++r) {
        int f = wv * 10 + r;
        float rin = sIn[f * DIM + lane];   // lane d holds in[f][d]
        float acc = 0.f;
        #pragma unroll
        for (int d = 0; d < DIM; ++d) {
            float bv = __uint_as_float(
                __builtin_amdgcn_readlane(__float_as_uint(rin), d));
            acc = fmaf(bv, wcol[d], acc);
        }
        sXW[f * DIM + lane] = acc;
    }

    __syncthreads();

    // ---- pair phase: out[b, p*64 + d] = xw[i_p][d] * in[j_p][d] ----
    // ONLY change vs the 420.4us baseline: PLAIN stores instead of
    // __builtin_nontemporal_store (nt/sc0/sc1 streaming bypass suspected of
    // halving effective write BW vs the fill's 6.3 TB/s plain-store path).
    const f32x4* sXW4 = (const f32x4*)sXW;
    f32x4* out4 = (f32x4*)out + (size_t)b * OUT4;
    for (int idx = tid; idx < OUT4; idx += BLOCK) {
        int p = idx >> 4;          // 16 float4 per pair row
        int q = idx & 15;
        int i = sPi[p];
        int j = sPj[p];
        f32x4 a = sXW4[i * 16 + q];
        f32x4 v = sIn4[j * 16 + q];
        out4[idx] = a * v;
    }
}

extern "C" void kernel_launch(void* const* d_in, const int* in_sizes, int n_in,
                              void* d_out, int out_size, void* d_ws, size_t ws_size,
                              hipStream_t stream)
{
    const float* in = (const float*)d_in[0];   // [2048, 40, 64] fp32
    const float* w  = (const float*)d_in[1];   // [64, 64] fp32
    float* out = (float*)d_out;                // [2048, 780*64] fp32

    bilinear_fused<<<2048, BLOCK, 0, stream>>>(in, w, out);
}